// Round 3
// baseline (522.130 us; speedup 1.0000x reference)
//
#include <hip/hip_runtime.h>
#include <stdint.h>

#define EMB 1024

typedef unsigned short u16;
typedef __attribute__((ext_vector_type(8))) unsigned short u16x8;
typedef __attribute__((ext_vector_type(8))) __bf16 bf16x8;
typedef __attribute__((ext_vector_type(4))) float f32x4;

__device__ __forceinline__ u16 f2bf(float f) {
  union { float f; uint32_t u; } x; x.f = f;
  uint32_t u = x.u;
  u += 0x7fff + ((u >> 16) & 1u);   // round-to-nearest-even
  return (u16)(u >> 16);
}
__device__ __forceinline__ float bf2f(u16 u) {
  union { uint32_t u; float f; } x; x.u = ((uint32_t)u) << 16;
  return x.f;
}

// Load 8 contiguous elements at element-offset `off` from an external buffer
// that is either f32 (isf32=1) or bf16 (isf32=0); return as bf16x8 bits.
// Branch is wave-uniform (flag is uniform).
__device__ __forceinline__ u16x8 load8(int isf32, const void* p, size_t off) {
  if (isf32) {
    const float4* f = (const float4*)((const float*)p + off);
    float4 lo = f[0], hi = f[1];
    u16x8 r;
    r[0] = f2bf(lo.x); r[1] = f2bf(lo.y); r[2] = f2bf(lo.z); r[3] = f2bf(lo.w);
    r[4] = f2bf(hi.x); r[5] = f2bf(hi.y); r[6] = f2bf(hi.z); r[7] = f2bf(hi.w);
    return r;
  }
  return *(const u16x8*)((const u16*)p + off);
}

__device__ __forceinline__ float load1(int isf32, const void* p, size_t off) {
  return isf32 ? ((const float*)p)[off] : bf2f(((const u16*)p)[off]);
}

// Fingerprint `values`: bf16 data -> even halfwords are bf16 values of N(0,1)
// (exponent in [120,132] ~99% of the time); f32 data -> even halfwords are
// low mantissa halves (uniform bits, ~5% in range). flag=1 means f32.
__global__ void detect_kernel(const u16* vals, int* flag) {
  if (threadIdx.x == 0 && blockIdx.x == 0) {
    int cnt = 0;
    for (int i = 0; i < 64; i++) {
      const int e = (vals[2 * i] >> 7) & 0xFF;
      if (e >= 120 && e <= 132) cnt++;
    }
    *flag = (cnt < 48) ? 1 : 0;
  }
}

// C[M,N] = X[M,K] @ W[N,K]^T + Bias[N], f32 accumulate, bf16 MFMA compute.
// External operands (x_ext/w_ext/c_ext) follow *dflag dtype (f32 or bf16);
// internal operands are always bf16. 128x128 tile, 4 waves, 4x4 16x16x32 MFMA.
__global__ __launch_bounds__(256, 2) void gemm_bt_bias_kernel(
    const void* __restrict__ X, const void* __restrict__ W,
    const void* __restrict__ Bias, void* __restrict__ C,
    const int* __restrict__ dflag, int x_ext, int w_ext, int c_ext,
    int M, int N, int K)
{
  __shared__ __attribute__((aligned(16))) u16 Al[128 * 32];
  __shared__ __attribute__((aligned(16))) u16 Bl[128 * 32];

  const int f32flag = *dflag;
  const int fx = x_ext & f32flag;
  const int fw = w_ext & f32flag;
  const int fb = fw;               // bias dtype follows weights
  const int fc = c_ext & f32flag;

  const int tid  = threadIdx.x;
  const int lane = tid & 63;
  const int w    = tid >> 6;
  const int wm = w >> 1, wn = w & 1;
  const int r16 = lane & 15, quad = lane >> 4;

  const int bm = blockIdx.y * 128;
  const int bn = blockIdx.x * 128;

  // 512 8-element segments per 128x32 tile; thread covers seg tid and tid+256.
  const int s0 = tid, s1 = tid + 256;
  const int ar0 = s0 >> 2, ak0 = (s0 & 3) * 8;
  const int ar1 = s1 >> 2, ak1 = (s1 & 3) * 8;

  const size_t xo0 = (size_t)(bm + ar0) * K + ak0;
  const size_t xo1 = (size_t)(bm + ar1) * K + ak1;
  const size_t wo0 = (size_t)(bn + ar0) * K + ak0;
  const size_t wo1 = (size_t)(bn + ar1) * K + ak1;

  f32x4 acc[4][4];
#pragma unroll
  for (int i = 0; i < 4; i++)
#pragma unroll
    for (int j = 0; j < 4; j++)
      acc[i][j] = f32x4{0.f, 0.f, 0.f, 0.f};

  // prefetch k0 = 0
  u16x8 xa = load8(fx, X, xo0);
  u16x8 xb = load8(fx, X, xo1);
  u16x8 wa = load8(fw, W, wo0);
  u16x8 wb = load8(fw, W, wo1);

  for (int k0 = 0; k0 < K; k0 += 32) {
    *(u16x8*)&Al[s0 * 8] = xa;
    *(u16x8*)&Al[s1 * 8] = xb;
    *(u16x8*)&Bl[s0 * 8] = wa;
    *(u16x8*)&Bl[s1 * 8] = wb;
    __syncthreads();

    // prefetch next K-slice (wraps to 0 on last iter -- always valid addrs)
    const int kn = (k0 + 32 < K) ? (k0 + 32) : 0;
    xa = load8(fx, X, xo0 + kn);
    xb = load8(fx, X, xo1 + kn);
    wa = load8(fw, W, wo0 + kn);
    wb = load8(fw, W, wo1 + kn);

    bf16x8 a[4], b[4];
#pragma unroll
    for (int t = 0; t < 4; t++)
      a[t] = *(const bf16x8*)&Al[(wm * 64 + t * 16 + r16) * 32 + quad * 8];
#pragma unroll
    for (int t = 0; t < 4; t++)
      b[t] = *(const bf16x8*)&Bl[(wn * 64 + t * 16 + r16) * 32 + quad * 8];

#pragma unroll
    for (int tm = 0; tm < 4; tm++)
#pragma unroll
      for (int tn = 0; tn < 4; tn++)
        acc[tm][tn] = __builtin_amdgcn_mfma_f32_16x16x32_bf16(a[tm], b[tn], acc[tm][tn], 0, 0, 0);
    __syncthreads();
  }

  // C/D layout: col = lane&15, row = quad*4 + reg  (verified m89/m91)
#pragma unroll
  for (int tn = 0; tn < 4; tn++) {
    const int col = bn + wn * 64 + tn * 16 + r16;
    const float bias = load1(fb, Bias, col);
#pragma unroll
    for (int tm = 0; tm < 4; tm++) {
      const int row0 = bm + wm * 64 + tm * 16 + quad * 4;
#pragma unroll
      for (int r = 0; r < 4; r++) {
        const float val = acc[tm][tn][r] + bias;
        const size_t idx = (size_t)(row0 + r) * N + col;
        if (fc) ((float*)C)[idx] = val;
        else    ((u16*)C)[idx]   = f2bf(val);
      }
    }
  }
}

// Per-token head-mixing attention (all-internal bf16 buffers, unchanged):
// S = (Q Kt^T)/8 over 16 heads, softmax over g, O = S V. One wave per token.
// O aliases Q (each wave reads its Q before writing O) -> no __restrict__.
__global__ __launch_bounds__(256, 2) void attn_heads_kernel(
    const u16* Q, const u16* Km, const u16* V, u16* O)
{
  __shared__ __attribute__((aligned(16))) u16 P[4][16 * 32];

  const int tid = threadIdx.x, lane = tid & 63, w = tid >> 6;
  const int r16 = lane & 15, quad = lane >> 4;
  const size_t base = ((size_t)blockIdx.x * 4 + w) * EMB;

  // Q rows (head-major, d-contiguous) are exactly A-layout; K rows are B-layout.
  const bf16x8 aq0 = *(const bf16x8*)&Q[base + r16 * 64 + quad * 8];
  const bf16x8 aq1 = *(const bf16x8*)&Q[base + r16 * 64 + 32 + quad * 8];
  const bf16x8 bk0 = *(const bf16x8*)&Km[base + r16 * 64 + quad * 8];
  const bf16x8 bk1 = *(const bf16x8*)&Km[base + r16 * 64 + 32 + quad * 8];

  f32x4 s = f32x4{0.f, 0.f, 0.f, 0.f};
  s = __builtin_amdgcn_mfma_f32_16x16x32_bf16(aq0, bk0, s, 0, 0, 0);
  s = __builtin_amdgcn_mfma_f32_16x16x32_bf16(aq1, bk1, s, 0, 0, 0);
  // s[r] = S[h=quad*4+r][g=lane&15]

  float p[4];
#pragma unroll
  for (int r = 0; r < 4; r++) {
    float v = s[r] * 0.125f;             // 1/sqrt(64)
    float m = v;
#pragma unroll
    for (int d = 8; d; d >>= 1) m = fmaxf(m, __shfl_xor(m, d, 16));
    float e = __expf(v - m);
    float sum = e;
#pragma unroll
    for (int d = 8; d; d >>= 1) sum += __shfl_xor(sum, d, 16);
    p[r] = e / sum;
  }

  // P (C-layout) -> LDS [h][g], zero-padded to K=32 for the PV MFMA
#pragma unroll
  for (int r = 0; r < 4; r++) {
    P[w][(quad * 4 + r) * 32 + r16]      = f2bf(p[r]);
    P[w][(quad * 4 + r) * 32 + 16 + r16] = 0;
  }
  __syncthreads();

  const bf16x8 pa = *(const bf16x8*)&P[w][r16 * 32 + quad * 8];  // A-frag of P

#pragma unroll
  for (int c = 0; c < 4; c++) {     // 4 chunks of 16 output dims
    union { u16 u[8]; bf16x8 v; } bv;
#pragma unroll
    for (int j = 0; j < 8; j++) {
      const int g = quad * 8 + j;
      bv.u[j] = (g < 16) ? V[base + g * 64 + c * 16 + r16] : (u16)0;
    }
    f32x4 o = f32x4{0.f, 0.f, 0.f, 0.f};
    o = __builtin_amdgcn_mfma_f32_16x16x32_bf16(pa, bv.v, o, 0, 0, 0);
#pragma unroll
    for (int r = 0; r < 4; r++)
      O[base + (size_t)(quad * 4 + r) * 64 + c * 16 + r16] = f2bf(o[r]);
  }
}

extern "C" void kernel_launch(void* const* d_in, const int* in_sizes, int n_in,
                              void* d_out, int out_size, void* d_ws, size_t ws_size,
                              hipStream_t stream)
{
  const void* values = d_in[0];
  const void* keys   = d_in[1];
  const void* query  = d_in[2];
  const void* Wv = d_in[3];
  const void* bv = d_in[4];
  const void* Wk = d_in[5];
  const void* bk = d_in[6];
  const void* Wq = d_in[7];
  const void* bq = d_in[8];
  const void* Wo = d_in[9];
  const void* bo = d_in[10];

  const int M = in_sizes[0] / EMB;   // 8192 tokens
  const int N = EMB, K = EMB;

  // ws layout: q | k (bf16, 16 MB each) | flag. v lives in d_out (dead before
  // the final GEMM overwrites it); attention output aliases q.
  u16* q = (u16*)d_ws;
  u16* k = q + (size_t)M * EMB;
  int* dflag = (int*)(k + (size_t)M * EMB);
  u16* v = (u16*)d_out;
  u16* ao = q;

  hipLaunchKernelGGL(detect_kernel, dim3(1), dim3(64), 0, stream,
                     (const u16*)values, dflag);

  dim3 blk(256, 1, 1);
  dim3 grid(N / 128, M / 128, 1);
  // external X, external W, internal C
  hipLaunchKernelGGL(gemm_bt_bias_kernel, grid, blk, 0, stream, values, Wv, bv, (void*)v, dflag, 1, 1, 0, M, N, K);
  hipLaunchKernelGGL(gemm_bt_bias_kernel, grid, blk, 0, stream, keys,   Wk, bk, (void*)k, dflag, 1, 1, 0, M, N, K);
  hipLaunchKernelGGL(gemm_bt_bias_kernel, grid, blk, 0, stream, query,  Wq, bq, (void*)q, dflag, 1, 1, 0, M, N, K);
  hipLaunchKernelGGL(attn_heads_kernel, dim3(M / 4, 1, 1), blk, 0, stream, q, k, v, ao);
  // internal X, external W, external C
  hipLaunchKernelGGL(gemm_bt_bias_kernel, grid, blk, 0, stream, (const void*)ao, Wo, bo, d_out, dflag, 0, 1, 1, M, N, K);
}